// Round 8
// baseline (145.227 us; speedup 1.0000x reference)
//
#include <hip/hip_runtime.h>

#define BB 4
#define NN 4096
#define GG 1024
#define CC 32
#define NSIG 4
#define PVALS 132          // 128 agg + 4 dens per (b,g)
#define NT 128             // points per LDS tile
#define KS_PER_TILE (NT / 32)
#define NCHUNK 16

// sigma = {0.01, 0.05, 0.1, 0.2} -> k = -0.5/sigma^2 = {-5000, -200, -50, -12.5}
// w(0.1)=w(0.2)^4, w(0.05)=w(0.1)^4 (repeated squaring); exp2 only for 0.2, 0.01.
#define C3 (-18.033688011112042f)   // -12.5/ln2  (sigma=0.2)
#define C0 (-7213.4752044448170f)   // -5000/ln2  (sigma=0.01)

typedef __attribute__((ext_vector_type(8))) short bf16x8;
typedef __attribute__((ext_vector_type(4))) float f32x4;

union frag_u { unsigned u[4]; bf16x8 v; };

// round-to-nearest f32->bf16 pair pack
__device__ __forceinline__ unsigned pack_bf16(float lo, float hi) {
    unsigned a = __float_as_uint(lo) + 0x8000u;
    unsigned b = __float_as_uint(hi) + 0x8000u;
    return __builtin_amdgcn_perm(b, a, 0x07060302u);
}

// Block = 4 waves, covers 64 g's (wave w -> 16 g's), one n-chunk of 256
// points staged as two 128-point LDS tiles (R2-verified staging/compute).
// Epilogue: per-wave atomicAdd into the 2.2 MB global accumulator.
__global__ __launch_bounds__(256) void gsc_fused_kernel(
    const float* __restrict__ px, const float* __restrict__ pf,
    const float* __restrict__ pm, const float* __restrict__ gx,
    float* __restrict__ gacc)
{
    __shared__ __align__(16) unsigned sfeat[KS_PER_TILE * 2 * 64 * 4]; // 8 KB
    __shared__ float sx[NT];
    __shared__ float sm[NT];

    const int tid = threadIdx.x;
    const int w   = tid >> 6;
    const int l   = tid & 63;
    const int q   = l >> 4;     // quad
    const int cl  = l & 15;

    int bid = blockIdx.x;
    const int gg = bid % (GG / 64);          // fastest: 16 blocks share a chunk
    bid /= (GG / 64);
    const int nc = bid % NCHUNK;
    const int b  = bid / NCHUNK;
    const int gbase = gg * 64 + w * 16;

    // A-operand layout: A[m = lane&15][k = quad*8 + j] -> lane's g = gbase+cl
    const float gxv = gx[gbase + cl];

    f32x4 acc[NSIG][2];
    f32x4 dacc[NSIG];
#pragma unroll
    for (int s = 0; s < NSIG; ++s) {
        acc[s][0] = (f32x4){0.f, 0.f, 0.f, 0.f};
        acc[s][1] = (f32x4){0.f, 0.f, 0.f, 0.f};
        dacc[s]   = (f32x4){0.f, 0.f, 0.f, 0.f};
    }

    const float* fb = pf + (size_t)b * NN * CC;
    const float* xb = px + (size_t)b * NN;
    const float* mb = pm + (size_t)b * NN;

    const int chunk   = NN / NCHUNK;         // 256
    const int n_begin = nc * chunk;

    const int sc   = tid & 31;   // staging: channel
    const int snp0 = tid >> 5;   // staging: n-pair base

    for (int n0 = n_begin; n0 < n_begin + chunk; n0 += NT) {
        __syncthreads();
        // ---- stage feat*mask as bf16 into frag-order LDS (R2-verified) ----
#pragma unroll
        for (int it = 0; it < NT / 16; ++it) {
            const int np = snp0 + it * 8;    // n-pair 0..63
            const int nl = np * 2;
            const int ng = n0 + nl;
            const float m0 = mb[ng], m1 = mb[ng + 1];
            const float f0 = fb[(size_t)ng * CC + sc] * m0;
            const float f1 = fb[(size_t)(ng + 1) * CC + sc] * m1;
            const unsigned pk = pack_bf16(f0, f1);
            const int ks = nl >> 5, qq = (nl >> 3) & 3, j = nl & 7, h = sc >> 4;
            sfeat[(((ks * 2 + h) * 64) + ((qq << 4) | (sc & 15))) * 4 + (j >> 1)] = pk;
        }
        if (tid < NT)          sx[tid]      = xb[n0 + tid];
        else if (tid < 2 * NT) sm[tid - NT] = mb[n0 + tid - NT];
        __syncthreads();

#pragma unroll
        for (int ks = 0; ks < KS_PER_TILE; ++ks) {
            const float* xp = &sx[ks * 32 + q * 8];
            const float* mp = &sm[ks * 32 + q * 8];
            float tt[8];
#pragma unroll
            for (int j = 0; j < 8; ++j) { const float dx = xp[j] - gxv; tt[j] = dx * dx; }

            frag_u a0, a1, a2, a3, am;
#pragma unroll
            for (int j = 0; j < 8; j += 2) {
                const float w3a = __builtin_amdgcn_exp2f(tt[j]     * C3);
                const float w3b = __builtin_amdgcn_exp2f(tt[j + 1] * C3);
                float s;
                s = w3a * w3a; const float w2a = s * s;   // ^4 -> sigma 0.1
                s = w3b * w3b; const float w2b = s * s;
                s = w2a * w2a; const float w1a = s * s;   // ^4 -> sigma 0.05
                s = w2b * w2b; const float w1b = s * s;
                const float w0a = __builtin_amdgcn_exp2f(tt[j]     * C0);
                const float w0b = __builtin_amdgcn_exp2f(tt[j + 1] * C0);
                a3.u[j >> 1] = pack_bf16(w3a, w3b);
                a2.u[j >> 1] = pack_bf16(w2a, w2b);
                a1.u[j >> 1] = pack_bf16(w1a, w1b);
                a0.u[j >> 1] = pack_bf16(w0a, w0b);
                am.u[j >> 1] = pack_bf16(mp[j], mp[j + 1]);
            }

            const bf16x8* sfv = (const bf16x8*)sfeat;
            const bf16x8 bf0 = sfv[(ks * 2 + 0) * 64 + l];
            const bf16x8 bf1 = sfv[(ks * 2 + 1) * 64 + l];

            acc[0][0] = __builtin_amdgcn_mfma_f32_16x16x32_bf16(a0.v, bf0, acc[0][0], 0, 0, 0);
            acc[0][1] = __builtin_amdgcn_mfma_f32_16x16x32_bf16(a0.v, bf1, acc[0][1], 0, 0, 0);
            dacc[0]   = __builtin_amdgcn_mfma_f32_16x16x32_bf16(a0.v, am.v, dacc[0], 0, 0, 0);
            acc[1][0] = __builtin_amdgcn_mfma_f32_16x16x32_bf16(a1.v, bf0, acc[1][0], 0, 0, 0);
            acc[1][1] = __builtin_amdgcn_mfma_f32_16x16x32_bf16(a1.v, bf1, acc[1][1], 0, 0, 0);
            dacc[1]   = __builtin_amdgcn_mfma_f32_16x16x32_bf16(a1.v, am.v, dacc[1], 0, 0, 0);
            acc[2][0] = __builtin_amdgcn_mfma_f32_16x16x32_bf16(a2.v, bf0, acc[2][0], 0, 0, 0);
            acc[2][1] = __builtin_amdgcn_mfma_f32_16x16x32_bf16(a2.v, bf1, acc[2][1], 0, 0, 0);
            dacc[2]   = __builtin_amdgcn_mfma_f32_16x16x32_bf16(a2.v, am.v, dacc[2], 0, 0, 0);
            acc[3][0] = __builtin_amdgcn_mfma_f32_16x16x32_bf16(a3.v, bf0, acc[3][0], 0, 0, 0);
            acc[3][1] = __builtin_amdgcn_mfma_f32_16x16x32_bf16(a3.v, bf1, acc[3][1], 0, 0, 0);
            dacc[3]   = __builtin_amdgcn_mfma_f32_16x16x32_bf16(a3.v, am.v, dacc[3], 0, 0, 0);
        }
    }

    // ---- epilogue: atomic accumulate. C/D layout: col(c) = lane&15 (+16h),
    // row(g) = quad*4+reg.
    float* base = gacc + ((size_t)b * GG + gbase) * PVALS;
#pragma unroll
    for (int s = 0; s < NSIG; ++s)
#pragma unroll
        for (int h = 0; h < 2; ++h)
#pragma unroll
            for (int r = 0; r < 4; ++r)
                atomicAdd(&base[(q * 4 + r) * PVALS + s * 32 + h * 16 + cl],
                          acc[s][h][r]);
    if (cl == 0) {
#pragma unroll
        for (int s = 0; s < NSIG; ++s)
#pragma unroll
            for (int r = 0; r < 4; ++r)
                atomicAdd(&base[(q * 4 + r) * PVALS + 128 + s], dacc[s][r]);
    }
}

// ---- divide: read L2-hot 2.2 MB accumulator, write final outputs ----
__global__ __launch_bounds__(128) void gsc_div_kernel(
    const float* __restrict__ gacc, float* __restrict__ out0,
    float* __restrict__ out1)
{
    const size_t bg = blockIdx.x;
    const int v = threadIdx.x;   // 0..127 -> (s = v>>5, c = v&31)
    const float* p = gacc + bg * PVALS;
    const float dn = p[128 + (v >> 5)];
    out0[bg * 128 + v] = p[v] / fmaxf(dn, 1e-6f);
    if (v < NSIG) out1[bg * NSIG + v] = p[128 + v];
}

extern "C" void kernel_launch(void* const* d_in, const int* in_sizes, int n_in,
                              void* d_out, int out_size, void* d_ws, size_t ws_size,
                              hipStream_t stream) {
    const float* px = (const float*)d_in[0];  // [B,N]
    const float* pf = (const float*)d_in[1];  // [B,N,C]
    const float* pm = (const float*)d_in[2];  // [B,N]
    const float* gx = (const float*)d_in[3];  // [G]
    float* out0 = (float*)d_out;                          // [B,G,4*C]
    float* out1 = out0 + (size_t)BB * GG * NSIG * CC;     // [B,G,4]

    float* gacc = (float*)d_ws;                           // [B,G,132] = 2.2 MB
    hipMemsetAsync(gacc, 0, (size_t)BB * GG * PVALS * sizeof(float), stream);

    gsc_fused_kernel<<<dim3(BB * NCHUNK * (GG / 64)), dim3(256), 0, stream>>>(
        px, pf, pm, gx, gacc);
    gsc_div_kernel<<<dim3(BB * GG), dim3(128), 0, stream>>>(gacc, out0, out1);
}

// Round 11
// 96.269 us; speedup vs baseline: 1.5086x; 1.5086x over previous
//
#include <hip/hip_runtime.h>

#define BB 4
#define NN 4096
#define GG 1024
#define CC 32
#define NSIG 4
#define PVALS 132          // 128 agg + 4 dens per (b,g)
#define NT 128             // points per LDS tile
#define KS_PER_TILE (NT / 32)
#define NCHUNK 16

// sigma = {0.01, 0.05, 0.1, 0.2} -> k = -0.5/sigma^2 = {-5000, -200, -50, -12.5}
// exp(k t) = exp2(t * k/ln2), one v_exp_f32 per sigma (no ladder).
#define C0 (-7213.4752044448170f)   // sigma=0.01
#define C1 (-288.53900817779268f)   // sigma=0.05
#define C2 (-72.134752044448170f)   // sigma=0.1
#define C3 (-18.033688011112042f)   // sigma=0.2

typedef __attribute__((ext_vector_type(8))) short bf16x8;
typedef __attribute__((ext_vector_type(4))) float f32x4;

union frag_u { unsigned u[4]; bf16x8 v; };

// round-to-nearest f32->bf16 pair pack
__device__ __forceinline__ unsigned pack_bf16(float lo, float hi) {
    unsigned a = __float_as_uint(lo) + 0x8000u;
    unsigned b = __float_as_uint(hi) + 0x8000u;
    return __builtin_amdgcn_perm(b, a, 0x07060302u);
}

// Block = 8 waves (512 thr) over 64 g's: wave = (g-subtile = w>>1) x
// (sigma-pair = w&1). Each wave: 16 g's x 2 sigmas -> acc = 16 regs + 2
// dens scalars (VALU), keeping combined VGPR+acc under the 128-reg
// occupancy cliff (R8 counters: 88 VGPR + 48 acc = 136 -> 2 waves/SIMD;
// this kernel targets 4 waves/SIMD). Sigma-pair 0 = {0.01, 0.05},
// pair 1 = {0.1, 0.2}; dens via fma + epilogue cross-quad shuffle.
__global__ __launch_bounds__(512) void gsc_fused_kernel(
    const float* __restrict__ px, const float* __restrict__ pf,
    const float* __restrict__ pm, const float* __restrict__ gx,
    float* __restrict__ partial)
{
    __shared__ __align__(16) unsigned sfeat[KS_PER_TILE * 2 * 64 * 4]; // 8 KB
    __shared__ float sx[NT];
    __shared__ float sm[NT];

    const int tid = threadIdx.x;
    const int w   = tid >> 6;        // 0..7
    const int l   = tid & 63;
    const int q   = l >> 4;          // quad
    const int cl  = l & 15;
    const int gt  = w >> 1;          // g-subtile 0..3
    const int sp  = w & 1;           // sigma-pair

    int bid = blockIdx.x;
    const int gg = bid % (GG / 64);
    bid /= (GG / 64);
    const int nc = bid % NCHUNK;
    const int b  = bid / NCHUNK;
    const int gbase = gg * 64 + gt * 16;

    // A-operand layout: A[m = lane&15][k = quad*8 + j] -> lane's g = gbase+cl
    const float gxv = gx[gbase + cl];
    const float cA = sp ? C2 : C0;   // acc[0]'s sigma: s = sp*2
    const float cB = sp ? C3 : C1;   // acc[1]'s sigma: s = sp*2+1

    f32x4 acc[2][2];
#pragma unroll
    for (int s = 0; s < 2; ++s) {
        acc[s][0] = (f32x4){0.f, 0.f, 0.f, 0.f};
        acc[s][1] = (f32x4){0.f, 0.f, 0.f, 0.f};
    }
    float densA = 0.0f, densB = 0.0f;

    const float* fb = pf + (size_t)b * NN * CC;
    const float* xb = px + (size_t)b * NN;
    const float* mb = pm + (size_t)b * NN;

    const int chunk   = NN / NCHUNK;         // 256
    const int n_begin = nc * chunk;

    const int sc   = tid & 31;   // staging: channel
    const int snp0 = tid >> 5;   // staging: n-pair base (0..15)

    for (int n0 = n_begin; n0 < n_begin + chunk; n0 += NT) {
        __syncthreads();
        // ---- stage feat*mask as bf16 into frag-order LDS ----
#pragma unroll
        for (int it = 0; it < NT / 32; ++it) {
            const int np = snp0 + it * 16;   // n-pair 0..63
            const int nl = np * 2;
            const int ng = n0 + nl;
            const float m0 = mb[ng], m1 = mb[ng + 1];
            const float f0 = fb[(size_t)ng * CC + sc] * m0;
            const float f1 = fb[(size_t)(ng + 1) * CC + sc] * m1;
            const unsigned pk = pack_bf16(f0, f1);
            const int ks = nl >> 5, qq = (nl >> 3) & 3, j = nl & 7, h = sc >> 4;
            sfeat[(((ks * 2 + h) * 64) + ((qq << 4) | (sc & 15))) * 4 + (j >> 1)] = pk;
        }
        if (tid < NT)          sx[tid]      = xb[n0 + tid];
        else if (tid < 2 * NT) sm[tid - NT] = mb[n0 + tid - NT];
        __syncthreads();

#pragma unroll
        for (int ks = 0; ks < KS_PER_TILE; ++ks) {
            const float* xp = &sx[ks * 32 + q * 8];
            const float* mp = &sm[ks * 32 + q * 8];
            float tt[8];
#pragma unroll
            for (int j = 0; j < 8; ++j) { const float dx = xp[j] - gxv; tt[j] = dx * dx; }

            frag_u aA, aB;
#pragma unroll
            for (int j = 0; j < 8; j += 2) {
                const float wA0 = __builtin_amdgcn_exp2f(tt[j]     * cA);
                const float wA1 = __builtin_amdgcn_exp2f(tt[j + 1] * cA);
                const float wB0 = __builtin_amdgcn_exp2f(tt[j]     * cB);
                const float wB1 = __builtin_amdgcn_exp2f(tt[j + 1] * cB);
                aA.u[j >> 1] = pack_bf16(wA0, wA1);
                aB.u[j >> 1] = pack_bf16(wB0, wB1);
                densA = fmaf(wA0, mp[j], fmaf(wA1, mp[j + 1], densA));
                densB = fmaf(wB0, mp[j], fmaf(wB1, mp[j + 1], densB));
            }

            const bf16x8* sfv = (const bf16x8*)sfeat;
            const bf16x8 bf0 = sfv[(ks * 2 + 0) * 64 + l];
            const bf16x8 bf1 = sfv[(ks * 2 + 1) * 64 + l];

            acc[0][0] = __builtin_amdgcn_mfma_f32_16x16x32_bf16(aA.v, bf0, acc[0][0], 0, 0, 0);
            acc[0][1] = __builtin_amdgcn_mfma_f32_16x16x32_bf16(aA.v, bf1, acc[0][1], 0, 0, 0);
            acc[1][0] = __builtin_amdgcn_mfma_f32_16x16x32_bf16(aB.v, bf0, acc[1][0], 0, 0, 0);
            acc[1][1] = __builtin_amdgcn_mfma_f32_16x16x32_bf16(aB.v, bf1, acc[1][1], 0, 0, 0);
        }
    }

    // ---- epilogue. agg C/D layout: col(c)=lane&15 (+16h), row(g)=quad*4+reg.
    // dens lives per-lane (g = cl, this quad's points): reduce across quads.
    densA += __shfl_xor(densA, 16, 64);
    densA += __shfl_xor(densA, 32, 64);
    densB += __shfl_xor(densB, 16, 64);
    densB += __shfl_xor(densB, 32, 64);

    float* p = partial + ((size_t)nc * BB * GG + (size_t)b * GG + gbase) * PVALS;
#pragma unroll
    for (int ss = 0; ss < 2; ++ss) {
        const int s = sp * 2 + ss;
#pragma unroll
        for (int h = 0; h < 2; ++h)
#pragma unroll
            for (int r = 0; r < 4; ++r)
                p[(q * 4 + r) * PVALS + s * 32 + h * 16 + cl] = acc[ss][h][r];
    }
    if (q == 0) {
        p[cl * PVALS + 128 + sp * 2 + 0] = densA;
        p[cl * PVALS + 128 + sp * 2 + 1] = densB;
    }
}

// ---- reduce: sum partials over n-chunks, divide, write final outputs ----
__global__ __launch_bounds__(128) void gsc_reduce_kernel(
    const float* __restrict__ partial, float* __restrict__ out0,
    float* __restrict__ out1, int nchunk)
{
    const size_t bg = blockIdx.x;
    const int v = threadIdx.x;   // 0..127 -> (s = v>>5, c = v&31)
    const int s = v >> 5;
    float num = 0.0f, dn = 0.0f;
    for (int nc = 0; nc < nchunk; ++nc) {
        const float* p = partial + ((size_t)nc * BB * GG + bg) * PVALS;
        num += p[v];
        dn  += p[128 + s];
    }
    out0[bg * 128 + v] = num / fmaxf(dn, 1e-6f);
    if (v < NSIG) {
        float d = 0.0f;
        for (int nc = 0; nc < nchunk; ++nc)
            d += partial[((size_t)nc * BB * GG + bg) * PVALS + 128 + v];
        out1[bg * NSIG + v] = d;
    }
}

extern "C" void kernel_launch(void* const* d_in, const int* in_sizes, int n_in,
                              void* d_out, int out_size, void* d_ws, size_t ws_size,
                              hipStream_t stream) {
    const float* px = (const float*)d_in[0];  // [B,N]
    const float* pf = (const float*)d_in[1];  // [B,N,C]
    const float* pm = (const float*)d_in[2];  // [B,N]
    const float* gx = (const float*)d_in[3];  // [G]
    float* out0 = (float*)d_out;                          // [B,G,4*C]
    float* out1 = out0 + (size_t)BB * GG * NSIG * CC;     // [B,G,4]

    float* partial = (float*)d_ws;   // NCHUNK * B*G*132 floats = 34.6 MB

    gsc_fused_kernel<<<dim3(BB * NCHUNK * (GG / 64)), dim3(512), 0, stream>>>(
        px, pf, pm, gx, partial);
    gsc_reduce_kernel<<<dim3(BB * GG), dim3(128), 0, stream>>>(
        partial, out0, out1, NCHUNK);
}